// Round 5
// baseline (513.434 us; speedup 1.0000x reference)
//
#include <hip/hip_runtime.h>

typedef __attribute__((ext_vector_type(8))) short short8;
typedef __attribute__((ext_vector_type(4))) float f32x4;

#define SS 1024
#define NB 16      // xconv macroblocks (16 rows each) [fallback path]
#define NBLK 64    // lstm blocks (4 rows each)
#define HROW 72    // bf16 elems per hbuf row (144 B, 16B-aligned)

__device__ __forceinline__ float sigmoidf_(float x) {
    return __builtin_amdgcn_rcpf(1.0f + __expf(-x));
}
__device__ __forceinline__ float tanhf_(float x) {
    return 1.0f - 2.0f * __builtin_amdgcn_rcpf(__expf(2.0f * x) + 1.0f);
}
__device__ __forceinline__ unsigned short f2bf(float f) {   // RNE f32->bf16
    unsigned int u = __float_as_uint(f);
    u += 0x7fffu + ((u >> 16) & 1u);
    return (unsigned short)(u >> 16);
}
__device__ __forceinline__ float h2f_(unsigned short u) {   // f16 bits -> f32
    _Float16 h;
    __builtin_memcpy(&h, &u, 2);
    return (float)h;
}

// lgkm-only barrier: global (vmcnt) prefetches stay in flight across it.
#define RAW_BARRIER() asm volatile("s_waitcnt lgkmcnt(0)\n\ts_barrier" ::: "memory")

#define MF(A, Bv, C) __builtin_amdgcn_mfma_f32_16x16x32_bf16(A, Bv, C, 0, 0, 0)

// ===========================================================================
// PATH 1 (needs 128 MB workspace): xz precompute + slim LSTM
// ===========================================================================

// ---- Kernel 1a: xz = x@W + bias, f16 [B*S][256] ---------------------------
// 256 blocks x 4 waves; each wave does 16 tiles of 16 rows x 256 cols.
// Fragment layout matches lstm kernel (A row=m, k=q*8+j; C row=q*4+r, col=m).
__global__ __launch_bounds__(256)
void xzgemm(const float* __restrict__ x, const float* __restrict__ wk,
            const float* __restrict__ bias, _Float16* __restrict__ xz) {
    const int tid = threadIdx.x;
    const int l   = tid & 63;
    const int w   = tid >> 6;
    const int m   = l & 15;
    const int q   = l >> 4;

    short8 Bf[16][2];     // 16 col-tiles x 2 k-halves (static-indexed only)
    float  bv[16];
#pragma unroll
    for (int ct = 0; ct < 16; ++ct) {
        bv[ct] = bias[ct * 16 + m];
#pragma unroll
        for (int h2 = 0; h2 < 2; ++h2) {
            short8 v;
#pragma unroll
            for (int j = 0; j < 8; ++j)
                v[j] = (short)f2bf(wk[(h2 * 32 + q * 8 + j) * 256 + ct * 16 + m]);
            Bf[ct][h2] = v;
        }
    }

    const int wt = blockIdx.x * 4 + w;        // wave id 0..1023
    for (int it = 0; it < 16; ++it) {
        const int ti = wt * 16 + it;          // 16-row tile, 0..16383
        const float* __restrict__ xr = x + (size_t)(ti * 16 + m) * 64;
        const float4 a0 = *(const float4*)(xr + q * 8);
        const float4 a1 = *(const float4*)(xr + q * 8 + 4);
        const float4 b0 = *(const float4*)(xr + 32 + q * 8);
        const float4 b1 = *(const float4*)(xr + 32 + q * 8 + 4);
        short8 xa0, xa1;
        xa0[0] = (short)f2bf(a0.x); xa0[1] = (short)f2bf(a0.y);
        xa0[2] = (short)f2bf(a0.z); xa0[3] = (short)f2bf(a0.w);
        xa0[4] = (short)f2bf(a1.x); xa0[5] = (short)f2bf(a1.y);
        xa0[6] = (short)f2bf(a1.z); xa0[7] = (short)f2bf(a1.w);
        xa1[0] = (short)f2bf(b0.x); xa1[1] = (short)f2bf(b0.y);
        xa1[2] = (short)f2bf(b0.z); xa1[3] = (short)f2bf(b0.w);
        xa1[4] = (short)f2bf(b1.x); xa1[5] = (short)f2bf(b1.y);
        xa1[6] = (short)f2bf(b1.z); xa1[7] = (short)f2bf(b1.w);

        _Float16* __restrict__ ob = xz + (size_t)(ti * 16 + q * 4) * 256 + m;
#pragma unroll
        for (int ct = 0; ct < 16; ++ct) {
            const f32x4 c = {bv[ct], bv[ct], bv[ct], bv[ct]};
            const f32x4 z = MF(xa1, Bf[ct][1], MF(xa0, Bf[ct][0], c));
            ob[ct * 16 +   0] = (_Float16)z[0];
            ob[ct * 16 + 256] = (_Float16)z[1];
            ob[ct * 16 + 512] = (_Float16)z[2];
            ob[ct * 16 + 768] = (_Float16)z[3];
        }
    }
}

// ---- Kernel 1b: 4-row sparse-A LSTM, xz preloaded -------------------------
// Batch row b (0..3) -> A-row 4b (pads elsewhere); each lane computes 1 gate
// set (batch q, col n0) from z reg 0. xz enters as the MFMA C-init.
// Prefetch holds RAW f16 bits (ushort) so the f16->f32 cvt (the load's first
// consumer) sits at the use site 2 regions later, not at issue.
#define LOADB(VAR, G, KC) do {                                                \
    const int kb = ((KC) << 5) + (q << 3);                                    \
    const int nn = ((G) << 6) + n0;                                           \
    short8 v;                                                                 \
    v[0] = (short)f2bf(rk[(kb + 0) * 256 + nn]);                              \
    v[1] = (short)f2bf(rk[(kb + 1) * 256 + nn]);                              \
    v[2] = (short)f2bf(rk[(kb + 2) * 256 + nn]);                              \
    v[3] = (short)f2bf(rk[(kb + 3) * 256 + nn]);                              \
    v[4] = (short)f2bf(rk[(kb + 4) * 256 + nn]);                              \
    v[5] = (short)f2bf(rk[(kb + 5) * 256 + nn]);                              \
    v[6] = (short)f2bf(rk[(kb + 6) * 256 + nn]);                              \
    v[7] = (short)f2bf(rk[(kb + 7) * 256 + nn]);                              \
    VAR = v; } while (0)

#define REGION(T, PAR, P0, P1, P2, P3, DO_O) do {                              \
    const short8 ha0 = *(const short8*)&hbuf[(PAR) ^ 1][m * HROW + (q << 3)];  \
    const short8 ha1 = *(const short8*)&hbuf[(PAR) ^ 1][m * HROW + 32 + (q << 3)]; \
    const float f0 = h2f_(P0), f1 = h2f_(P1), f2 = h2f_(P2), f3 = h2f_(P3);    \
    const f32x4 ci = {f0, f0, f0, f0};                                         \
    const f32x4 cf = {f1, f1, f1, f1};                                         \
    const f32x4 cg = {f2, f2, f2, f2};                                         \
    const f32x4 co = {f3, f3, f3, f3};                                         \
    const f32x4 z0 = MF(ha1, BH01, MF(ha0, BH00, ci));                         \
    const f32x4 z1 = MF(ha1, BH11, MF(ha0, BH10, cf));                         \
    const f32x4 z2 = MF(ha1, BH21, MF(ha0, BH20, cg));                         \
    const f32x4 z3 = MF(ha1, BH31, MF(ha0, BH30, co));                         \
    { const size_t xo = (size_t)(((T) + 2 < SS) ? (T) + 2 : SS - 1) << 8;      \
      P0 = xzl[xo];       P1 = xzl[xo + 64];                                   \
      P2 = xzl[xo + 128]; P3 = xzl[xo + 192]; }                                \
    if ((DO_O) && w == 0) {                                                    \
        const f32x4 zzero = {0.f, 0.f, 0.f, 0.f};                              \
        const f32x4 z4 = MF(ha1, BD1, MF(ha0, BD0, zzero));                    \
        if (m == 0) {                                                          \
            out[((size_t)((bb << 2) + q) << 10) + (T) - 1] =                   \
                sigmoidf_(z4[0] + db0);                                        \
        }                                                                      \
    }                                                                          \
    { const float ig = sigmoidf_(z0[0]), fg = sigmoidf_(z1[0]),                \
                  og = sigmoidf_(z3[0]);                                       \
      cc0 = fg * cc0 + ig * tanhf_(z2[0]);                                     \
      const float h0 = og * tanhf_(cc0);                                       \
      hbuf[PAR][(q << 2) * HROW + n0] = (short)f2bf(h0); }                     \
    RAW_BARRIER();                                                             \
} while (0)

__global__ __launch_bounds__(256, 1)
void lstm_xz(const unsigned short* __restrict__ xz, const float* __restrict__ rk,
             const float* __restrict__ dw, const float* __restrict__ db,
             float* __restrict__ out) {
    const int bb  = blockIdx.x;               // 0..63, 4 batch rows each
    const int tid = threadIdx.x;
    const int l   = tid & 63;
    const int w   = tid >> 6;
    const int m   = l & 15;
    const int q   = l >> 4;
    const int n0  = (w << 4) + m;

    __shared__ short hbuf[2][16 * HROW];      // 4.6 KB, double-buffered h

    for (int i = tid; i < 2 * 16 * HROW; i += 256) ((short*)hbuf)[i] = 0;
    __syncthreads();

    short8 BH00, BH01, BH10, BH11, BH20, BH21, BH30, BH31;
    LOADB(BH00, 0, 0); LOADB(BH01, 0, 1);
    LOADB(BH10, 1, 0); LOADB(BH11, 1, 1);
    LOADB(BH20, 2, 0); LOADB(BH21, 2, 1);
    LOADB(BH30, 3, 0); LOADB(BH31, 3, 1);

    // Dense B-fragment: column 0 = dw, all other columns 0.
    short8 BD0, BD1;
    {
        short8 v0 = {0, 0, 0, 0, 0, 0, 0, 0}, v1 = v0;
        if (m == 0) {
#pragma unroll
            for (int i = 0; i < 8; ++i) v0[i] = (short)f2bf(dw[(q << 3) + i]);
#pragma unroll
            for (int i = 0; i < 8; ++i) v1[i] = (short)f2bf(dw[32 + (q << 3) + i]);
        }
        BD0 = v0; BD1 = v1;
    }
    const float db0 = db[0];

    // Per-lane xz base: batch bb*4+q, col n0; gate g at +g*64, step t at +t*256.
    const unsigned short* __restrict__ xzl =
        xz + ((size_t)((bb << 2) + q) << 18) + n0;

    unsigned short pA0 = xzl[0],   pA1 = xzl[64];
    unsigned short pA2 = xzl[128], pA3 = xzl[192];
    unsigned short pB0 = xzl[256 +   0], pB1 = xzl[256 +  64];
    unsigned short pB2 = xzl[256 + 128], pB3 = xzl[256 + 192];

    float cc0 = 0.f;

    REGION(0, 0, pA0, pA1, pA2, pA3, 0);
    REGION(1, 1, pB0, pB1, pB2, pB3, 1);
    for (int t = 2; t < SS; t += 2) {
        REGION(t,     0, pA0, pA1, pA2, pA3, 1);
        REGION(t + 1, 1, pB0, pB1, pB2, pB3, 1);
    }
    if (w == 0) {   // dense for h_{SS-1}
        const short8 ha0 = *(const short8*)&hbuf[1][m * HROW + (q << 3)];
        const short8 ha1 = *(const short8*)&hbuf[1][m * HROW + 32 + (q << 3)];
        const f32x4 zzero = {0.f, 0.f, 0.f, 0.f};
        const f32x4 z4 = MF(ha1, BD1, MF(ha0, BD0, zzero));
        if (m == 0) {
            out[((size_t)((bb << 2) + q) << 10) + SS - 1] =
                sigmoidf_(z4[0] + db0);
        }
    }
}

// ===========================================================================
// PATH 2 (fallback, 33.5 MB workspace): round-2 verified kernels (343 us)
// ===========================================================================

__global__ __launch_bounds__(256)
void xconv(const float* __restrict__ x, short* __restrict__ xA) {
    const int gid  = blockIdx.x * 256 + threadIdx.x;
    const int half = gid & 1;
    const int q    = (gid >> 1) & 3;
    const int m    = (gid >> 3) & 15;
    const int bt   = gid >> 7;                // mb*1024 + t
    const int t    = bt & 1023;
    const int mb   = bt >> 10;
    const float* __restrict__ xr =
        x + (((size_t)(mb * 16 + m)) * SS + t) * 64 + half * 32 + q * 8;
    const float4 a = *(const float4*)xr;
    const float4 b = *(const float4*)(xr + 4);
    short8 o;
    o[0] = (short)f2bf(a.x); o[1] = (short)f2bf(a.y);
    o[2] = (short)f2bf(a.z); o[3] = (short)f2bf(a.w);
    o[4] = (short)f2bf(b.x); o[5] = (short)f2bf(b.y);
    o[6] = (short)f2bf(b.z); o[7] = (short)f2bf(b.w);
    ((short8*)xA)[gid] = o;
}

#define LOADB_FB(VAR, G, KC) do {                                             \
    const float* __restrict__ Wsrc = ((KC) < 2) ? rk : wk;                    \
    const int kb = (((KC) & 1) << 5) + (q << 3);                              \
    const int nn = ((G) << 6) + n0;                                           \
    short8 v;                                                                 \
    v[0] = (short)f2bf(Wsrc[(kb + 0) * 256 + nn]);                            \
    v[1] = (short)f2bf(Wsrc[(kb + 1) * 256 + nn]);                            \
    v[2] = (short)f2bf(Wsrc[(kb + 2) * 256 + nn]);                            \
    v[3] = (short)f2bf(Wsrc[(kb + 3) * 256 + nn]);                            \
    v[4] = (short)f2bf(Wsrc[(kb + 4) * 256 + nn]);                            \
    v[5] = (short)f2bf(Wsrc[(kb + 5) * 256 + nn]);                            \
    v[6] = (short)f2bf(Wsrc[(kb + 6) * 256 + nn]);                            \
    v[7] = (short)f2bf(Wsrc[(kb + 7) * 256 + nn]);                            \
    VAR = v; } while (0)

#define XIDX(T) (xb0 + ((size_t)(T) << 7))

#define REGION_FB(T, PAR, XC0, XC1, XN0, XN1, QC0, QC1, QC2, QC3,              \
               QN0, QN1, QN2, QN3, DO_O) do {                                  \
    const short8 ha0 = *(const short8*)&hbuf[(PAR) ^ 1][m * HROW + (q << 3)];  \
    const short8 ha1 = *(const short8*)&hbuf[(PAR) ^ 1][m * HROW + 32 + (q << 3)]; \
    { const size_t o = XIDX(((T) + 4 < SS) ? (T) + 4 : SS - 1);                \
      XC0 = xsrc[o]; XC1 = xsrc[o + 1]; }                                      \
    QN0 = MF(XN1, BX01, MF(XN0, BX00, cb0));                                   \
    QN1 = MF(XN1, BX11, MF(XN0, BX10, cb1));                                   \
    QN2 = MF(XN1, BX21, MF(XN0, BX20, cb2));                                   \
    QN3 = MF(XN1, BX31, MF(XN0, BX30, cb3));                                   \
    const f32x4 z0 = MF(ha1, BH01, MF(ha0, BH00, QC0));                        \
    const f32x4 z1 = MF(ha1, BH11, MF(ha0, BH10, QC1));                        \
    const f32x4 z2 = MF(ha1, BH21, MF(ha0, BH20, QC2));                        \
    const f32x4 z3 = MF(ha1, BH31, MF(ha0, BH30, QC3));                        \
    if ((DO_O) && w == 0) {                                                    \
        const f32x4 zzero = {0.f, 0.f, 0.f, 0.f};                              \
        const f32x4 z4 = MF(ha1, BD1, MF(ha0, BD0, zzero));                    \
        if (m == 0) {                                                          \
            out[((size_t)((bb << 2) + q) << 10) + (T) - 1] =                   \
                sigmoidf_(z4[0] + db0);                                        \
        }                                                                      \
    }                                                                          \
    { const float ig = sigmoidf_(z0[0]), fg = sigmoidf_(z1[0]),                \
                  og = sigmoidf_(z3[0]);                                       \
      cc0 = fg * cc0 + ig * tanhf_(z2[0]);                                     \
      const float h0 = og * tanhf_(cc0);                                       \
      hbuf[PAR][(q << 2) * HROW + n0] = (short)f2bf(h0); }                     \
    RAW_BARRIER();                                                             \
} while (0)

__global__ __launch_bounds__(256, 1)
void lstm_fb(const short* __restrict__ xA, const float* __restrict__ wk,
             const float* __restrict__ rk, const float* __restrict__ bias,
             const float* __restrict__ dw, const float* __restrict__ db,
             float* __restrict__ out) {
    const int bb  = blockIdx.x;
    const int tid = threadIdx.x;
    const int l   = tid & 63;
    const int w   = tid >> 6;
    const int m   = l & 15;
    const int q   = l >> 4;
    const int n0  = (w << 4) + m;

    __shared__ short hbuf[2][16 * HROW];

    for (int i = tid; i < 2 * 16 * HROW; i += 256) ((short*)hbuf)[i] = 0;
    __syncthreads();

    short8 BH00, BH01, BH10, BH11, BH20, BH21, BH30, BH31;
    short8 BX00, BX01, BX10, BX11, BX20, BX21, BX30, BX31;
    LOADB_FB(BH00, 0, 0); LOADB_FB(BH01, 0, 1); LOADB_FB(BX00, 0, 2); LOADB_FB(BX01, 0, 3);
    LOADB_FB(BH10, 1, 0); LOADB_FB(BH11, 1, 1); LOADB_FB(BX10, 1, 2); LOADB_FB(BX11, 1, 3);
    LOADB_FB(BH20, 2, 0); LOADB_FB(BH21, 2, 1); LOADB_FB(BX20, 2, 2); LOADB_FB(BX21, 2, 3);
    LOADB_FB(BH30, 3, 0); LOADB_FB(BH31, 3, 1); LOADB_FB(BX30, 3, 2); LOADB_FB(BX31, 3, 3);

    short8 BD0, BD1;
    {
        short8 v0 = {0, 0, 0, 0, 0, 0, 0, 0}, v1 = v0;
        if (m == 0) {
#pragma unroll
            for (int i = 0; i < 8; ++i) v0[i] = (short)f2bf(dw[(q << 3) + i]);
#pragma unroll
            for (int i = 0; i < 8; ++i) v1[i] = (short)f2bf(dw[32 + (q << 3) + i]);
        }
        BD0 = v0; BD1 = v1;
    }

    const float b0 = bias[n0], b1 = bias[64 + n0];
    const float b2 = bias[128 + n0], b3 = bias[192 + n0];
    const f32x4 cb0 = {b0, b0, b0, b0};
    const f32x4 cb1 = {b1, b1, b1, b1};
    const f32x4 cb2 = {b2, b2, b2, b2};
    const f32x4 cb3 = {b3, b3, b3, b3};
    const float db0 = db[0];

    const int mb  = bb >> 2;
    const int l16 = ((bb & 3) << 2) | (m >> 2);
    const size_t xb0 = (size_t)mb * 131072 + (size_t)(((l16 << 2) | q) << 1);

    const short8* __restrict__ xsrc = (const short8*)xA;
    short8 X00 = xsrc[XIDX(0)], X01 = xsrc[XIDX(0) + 1];
    short8 X10 = xsrc[XIDX(1)], X11 = xsrc[XIDX(1) + 1];
    short8 X20 = xsrc[XIDX(2)], X21 = xsrc[XIDX(2) + 1];
    short8 X30 = xsrc[XIDX(3)], X31 = xsrc[XIDX(3) + 1];

    f32x4 qA0 = MF(X01, BX01, MF(X00, BX00, cb0));
    f32x4 qA1 = MF(X01, BX11, MF(X00, BX10, cb1));
    f32x4 qA2 = MF(X01, BX21, MF(X00, BX20, cb2));
    f32x4 qA3 = MF(X01, BX31, MF(X00, BX30, cb3));
    f32x4 qB0, qB1, qB2, qB3;

    float cc0 = 0.f;

    REGION_FB(0, 0, X00, X01, X10, X11, qA0, qA1, qA2, qA3, qB0, qB1, qB2, qB3, 0);
    REGION_FB(1, 1, X10, X11, X20, X21, qB0, qB1, qB2, qB3, qA0, qA1, qA2, qA3, 1);
    REGION_FB(2, 0, X20, X21, X30, X31, qA0, qA1, qA2, qA3, qB0, qB1, qB2, qB3, 1);
    REGION_FB(3, 1, X30, X31, X00, X01, qB0, qB1, qB2, qB3, qA0, qA1, qA2, qA3, 1);
    for (int t = 4; t < SS; t += 4) {
        REGION_FB(t,     0, X00, X01, X10, X11, qA0, qA1, qA2, qA3, qB0, qB1, qB2, qB3, 1);
        REGION_FB(t + 1, 1, X10, X11, X20, X21, qB0, qB1, qB2, qB3, qA0, qA1, qA2, qA3, 1);
        REGION_FB(t + 2, 0, X20, X21, X30, X31, qA0, qA1, qA2, qA3, qB0, qB1, qB2, qB3, 1);
        REGION_FB(t + 3, 1, X30, X31, X00, X01, qB0, qB1, qB2, qB3, qA0, qA1, qA2, qA3, 1);
    }
    if (w == 0) {
        const short8 ha0 = *(const short8*)&hbuf[1][m * HROW + (q << 3)];
        const short8 ha1 = *(const short8*)&hbuf[1][m * HROW + 32 + (q << 3)];
        const f32x4 zzero = {0.f, 0.f, 0.f, 0.f};
        const f32x4 z4 = MF(ha1, BD1, MF(ha0, BD0, zzero));
        if (m == 0) {
            out[((size_t)((bb << 2) + q) << 10) + SS - 1] =
                sigmoidf_(z4[0] + db0);
        }
    }
}

// ============ Host ============
extern "C" void kernel_launch(void* const* d_in, const int* in_sizes, int n_in,
                              void* d_out, int out_size, void* d_ws, size_t ws_size,
                              hipStream_t stream) {
    const float* x    = (const float*)d_in[0];
    const float* wk   = (const float*)d_in[1];
    const float* rk   = (const float*)d_in[2];
    const float* bias = (const float*)d_in[3];
    const float* dw   = (const float*)d_in[4];
    const float* db   = (const float*)d_in[5];
    float* out = (float*)d_out;

    const size_t XZ_BYTES = (size_t)256 * 1024 * 256 * sizeof(_Float16); // 128 MB

    if (ws_size >= XZ_BYTES) {
        _Float16* xz = (_Float16*)d_ws;
        hipLaunchKernelGGL(xzgemm, dim3(256), dim3(256), 0, stream,
                           x, wk, bias, xz);
        hipLaunchKernelGGL(lstm_xz, dim3(NBLK), dim3(256), 0, stream,
                           (const unsigned short*)xz, rk, dw, db, out);
    } else {
        short* xA = (short*)d_ws;   // 33.5 MB
        hipLaunchKernelGGL(xconv, dim3(NB * 1024 * 128 / 256), dim3(256), 0,
                           stream, x, xA);
        hipLaunchKernelGGL(lstm_fb, dim3(NBLK), dim3(256), 0, stream,
                           xA, wk, rk, bias, dw, db, out);
    }
}

// Round 7
// 426.727 us; speedup vs baseline: 1.2032x; 1.2032x over previous
//
#include <hip/hip_runtime.h>

typedef __attribute__((ext_vector_type(8))) short short8;
typedef __attribute__((ext_vector_type(4))) float f32x4;

#define SS 1024
#define NBLK 64    // lstm blocks (4 batch rows each)
#define HROW 72    // bf16 elems per hbuf row (144 B, 16B-aligned)

__device__ __forceinline__ float sigmoidf_(float x) {
    return __builtin_amdgcn_rcpf(1.0f + __expf(-x));
}
__device__ __forceinline__ float tanhf_(float x) {
    return 1.0f - 2.0f * __builtin_amdgcn_rcpf(__expf(2.0f * x) + 1.0f);
}
__device__ __forceinline__ unsigned short f2bf(float f) {   // RNE f32->bf16
    unsigned int u = __float_as_uint(f);
    u += 0x7fffu + ((u >> 16) & 1u);
    return (unsigned short)(u >> 16);
}
__device__ __forceinline__ float bf2f(unsigned short u) {
    return __uint_as_float((unsigned int)u << 16);
}
__device__ __forceinline__ float h2f_lo(unsigned int u) {
    _Float16 h; unsigned short s = (unsigned short)(u & 0xffffu);
    __builtin_memcpy(&h, &s, 2); return (float)h;
}
__device__ __forceinline__ float h2f_hi(unsigned int u) {
    _Float16 h; unsigned short s = (unsigned short)(u >> 16);
    __builtin_memcpy(&h, &s, 2); return (float)h;
}
__device__ __forceinline__ unsigned int pkf16(float a, float b) {
    auto p = __builtin_amdgcn_cvt_pkrtz(a, b);   // __fp16 ext_vector(2)
    unsigned int u; __builtin_memcpy(&u, &p, 4); return u;
}

// lgkm-only barrier: global (vmcnt) prefetches/stores stay in flight.
#define RAW_BARRIER() asm volatile("s_waitcnt lgkmcnt(0)\n\ts_barrier" ::: "memory")

#define MF(A, Bv, C) __builtin_amdgcn_mfma_f32_16x16x32_bf16(A, Bv, C, 0, 0, 0)

// ============ Kernel 1: xz = x@W + bias, f16 gate-interleaved ==============
// Layout: xzp[(b*1024+t)*64 + n] = uint2{ pk(zi,zf), pk(zc,zo) }  (8 B).
// 256 blocks x 4 waves; each wave does 16 tiles of 16 rows x 256 cols.
// Stores: per (ctn,r) one dwordx2/lane, 16 lanes -> 128 B contiguous.
__global__ __launch_bounds__(256)
void xzgemm(const float* __restrict__ x, const float* __restrict__ wk,
            const float* __restrict__ bias, uint2* __restrict__ xzp) {
    const int tid = threadIdx.x;
    const int l   = tid & 63;
    const int w   = tid >> 6;
    const int m   = l & 15;
    const int q   = l >> 4;

    short8 Bf[16][2];     // 16 col-tiles x 2 k-halves (static-indexed only)
    float  bv[16];
#pragma unroll
    for (int ct = 0; ct < 16; ++ct) {
        bv[ct] = bias[ct * 16 + m];
#pragma unroll
        for (int h2 = 0; h2 < 2; ++h2) {
            short8 v;
#pragma unroll
            for (int j = 0; j < 8; ++j)
                v[j] = (short)f2bf(wk[(h2 * 32 + q * 8 + j) * 256 + ct * 16 + m]);
            Bf[ct][h2] = v;
        }
    }

    const int wt = blockIdx.x * 4 + w;        // wave id 0..1023
    for (int it = 0; it < 16; ++it) {
        const int ti = wt * 16 + it;          // 16-row tile, 0..16383
        const float* __restrict__ xr = x + (size_t)(ti * 16 + m) * 64;
        const float4 a0 = *(const float4*)(xr + q * 8);
        const float4 a1 = *(const float4*)(xr + q * 8 + 4);
        const float4 b0 = *(const float4*)(xr + 32 + q * 8);
        const float4 b1 = *(const float4*)(xr + 32 + q * 8 + 4);
        short8 xa0, xa1;
        xa0[0] = (short)f2bf(a0.x); xa0[1] = (short)f2bf(a0.y);
        xa0[2] = (short)f2bf(a0.z); xa0[3] = (short)f2bf(a0.w);
        xa0[4] = (short)f2bf(a1.x); xa0[5] = (short)f2bf(a1.y);
        xa0[6] = (short)f2bf(a1.z); xa0[7] = (short)f2bf(a1.w);
        xa1[0] = (short)f2bf(b0.x); xa1[1] = (short)f2bf(b0.y);
        xa1[2] = (short)f2bf(b0.z); xa1[3] = (short)f2bf(b0.w);
        xa1[4] = (short)f2bf(b1.x); xa1[5] = (short)f2bf(b1.y);
        xa1[6] = (short)f2bf(b1.z); xa1[7] = (short)f2bf(b1.w);

#pragma unroll
        for (int ctn = 0; ctn < 4; ++ctn) {   // n-block; gates from ct=ctn+4g
            const f32x4 ci = {bv[ctn],      bv[ctn],      bv[ctn],      bv[ctn]};
            const f32x4 cf = {bv[ctn + 4],  bv[ctn + 4],  bv[ctn + 4],  bv[ctn + 4]};
            const f32x4 cc = {bv[ctn + 8],  bv[ctn + 8],  bv[ctn + 8],  bv[ctn + 8]};
            const f32x4 co = {bv[ctn + 12], bv[ctn + 12], bv[ctn + 12], bv[ctn + 12]};
            const f32x4 zi = MF(xa1, Bf[ctn][1],      MF(xa0, Bf[ctn][0],      ci));
            const f32x4 zf = MF(xa1, Bf[ctn + 4][1],  MF(xa0, Bf[ctn + 4][0],  cf));
            const f32x4 zc = MF(xa1, Bf[ctn + 8][1],  MF(xa0, Bf[ctn + 8][0],  cc));
            const f32x4 zo = MF(xa1, Bf[ctn + 12][1], MF(xa0, Bf[ctn + 12][0], co));
            uint2* __restrict__ ob =
                xzp + ((size_t)(ti * 16 + q * 4) * 64 + ctn * 16 + m);
#pragma unroll
            for (int r = 0; r < 4; ++r) {
                uint2 v;
                v.x = pkf16(zi[r], zf[r]);
                v.y = pkf16(zc[r], zo[r]);
                ob[(size_t)r * 64] = v;
            }
        }
    }
}

// ============ Kernel 2: 4-row sparse-A LSTM ================================
// Batch row b (0..3) -> A-row 4b (pads elsewhere); each lane computes 1 gate
// set (batch q, col n0) from z reg 0. xz (per-step dwordx2) is the C-init.
// DM==0: stream h to global (dense deferred). DM==1: inline dense via z4.
#define LOADB(VAR, G, KC) do {                                                \
    const int kb = ((KC) << 5) + (q << 3);                                    \
    const int nn = ((G) << 6) + n0;                                           \
    short8 v;                                                                 \
    v[0] = (short)f2bf(rk[(kb + 0) * 256 + nn]);                              \
    v[1] = (short)f2bf(rk[(kb + 1) * 256 + nn]);                              \
    v[2] = (short)f2bf(rk[(kb + 2) * 256 + nn]);                              \
    v[3] = (short)f2bf(rk[(kb + 3) * 256 + nn]);                              \
    v[4] = (short)f2bf(rk[(kb + 4) * 256 + nn]);                              \
    v[5] = (short)f2bf(rk[(kb + 5) * 256 + nn]);                              \
    v[6] = (short)f2bf(rk[(kb + 6) * 256 + nn]);                              \
    v[7] = (short)f2bf(rk[(kb + 7) * 256 + nn]);                              \
    VAR = v; } while (0)

// Order: ha reads -> xz(T+2) load -> unpack/splat -> c-gate MFMA chain first
// (tanh chain starts earliest), o/i/f overlap it -> gates -> h write -> barrier.
#define REGION(T, PAR, P, DO_O) do {                                           \
    const short8 ha0 = *(const short8*)&hbuf[(PAR) ^ 1][m * HROW + (q << 3)];  \
    const short8 ha1 = *(const short8*)&hbuf[(PAR) ^ 1][m * HROW + 32 + (q << 3)]; \
    const uint2 cur = P;                                                       \
    P = xb[(size_t)(((T) + 2 < SS) ? (T) + 2 : SS - 1) << 6];                  \
    const float vi = h2f_lo(cur.x), vf = h2f_hi(cur.x);                        \
    const float vc = h2f_lo(cur.y), vo = h2f_hi(cur.y);                        \
    const f32x4 cgi = {vi, vi, vi, vi};                                        \
    const f32x4 cgf = {vf, vf, vf, vf};                                        \
    const f32x4 cgc = {vc, vc, vc, vc};                                        \
    const f32x4 cgo = {vo, vo, vo, vo};                                        \
    const f32x4 zc = MF(ha1, BHC1, MF(ha0, BHC0, cgc));                        \
    const f32x4 zo = MF(ha1, BHO1, MF(ha0, BHO0, cgo));                        \
    const f32x4 zi = MF(ha1, BHI1, MF(ha0, BHI0, cgi));                        \
    const f32x4 zf = MF(ha1, BHF1, MF(ha0, BHF0, cgf));                        \
    if (DM == 1 && (DO_O) && w == 0) {                                         \
        const f32x4 zz = {0.f, 0.f, 0.f, 0.f};                                 \
        const f32x4 z4 = MF(ha1, BD1, MF(ha0, BD0, zz));                       \
        if (m == 0) {                                                          \
            out[((size_t)((bb << 2) + q) << 10) + (T) - 1] =                   \
                sigmoidf_(z4[0] + db0);                                        \
        }                                                                      \
    }                                                                          \
    const float tc = tanhf_(zc[0]);                                            \
    const float go = sigmoidf_(zo[0]);                                         \
    const float gi = sigmoidf_(zi[0]);                                         \
    const float gf = sigmoidf_(zf[0]);                                         \
    cc0 = gf * cc0 + gi * tc;                                                  \
    const float h0 = go * tanhf_(cc0);                                         \
    const unsigned short hb16 = f2bf(h0);                                      \
    hbuf[PAR][(q << 2) * HROW + n0] = (short)hb16;                             \
    if (DM == 0) hb[(size_t)(T) << 6] = hb16;                                  \
    RAW_BARRIER();                                                             \
} while (0)

template<int DM>
__global__ __launch_bounds__(256, 1)
void lstm_xz(const uint2* __restrict__ xzu, const float* __restrict__ rk,
             unsigned short* __restrict__ hg, const float* __restrict__ dw,
             const float* __restrict__ db, float* __restrict__ out) {
    const int bb  = blockIdx.x;               // 0..63, 4 batch rows each
    const int tid = threadIdx.x;
    const int l   = tid & 63;
    const int w   = tid >> 6;
    const int m   = l & 15;
    const int q   = l >> 4;
    const int n0  = (w << 4) + m;

    __shared__ short hbuf[2][16 * HROW];      // 4.6 KB, double-buffered h

    for (int i = tid; i < 2 * 16 * HROW; i += 256) ((short*)hbuf)[i] = 0;
    __syncthreads();

    short8 BHI0, BHI1, BHF0, BHF1, BHC0, BHC1, BHO0, BHO1;
    LOADB(BHI0, 0, 0); LOADB(BHI1, 0, 1);
    LOADB(BHF0, 1, 0); LOADB(BHF1, 1, 1);
    LOADB(BHC0, 2, 0); LOADB(BHC1, 2, 1);
    LOADB(BHO0, 3, 0); LOADB(BHO1, 3, 1);

    short8 BD0, BD1;      // dense B-fragment (col 0 = dw), used when DM==1
    {
        short8 v0 = {0, 0, 0, 0, 0, 0, 0, 0}, v1 = v0;
        if (m == 0) {
#pragma unroll
            for (int i = 0; i < 8; ++i) v0[i] = (short)f2bf(dw[(q << 3) + i]);
#pragma unroll
            for (int i = 0; i < 8; ++i) v1[i] = (short)f2bf(dw[32 + (q << 3) + i]);
        }
        BD0 = v0; BD1 = v1;
    }
    const float db0 = db[0];

    // Per-lane bases: row (b*1024+t), element n0 -> idx = row*64 + n0.
    const size_t base = ((size_t)((bb << 2) + q) << 16) + n0;
    const uint2* __restrict__ xb = xzu + base;
    unsigned short* __restrict__ hb = hg + base;

    uint2 PA = xb[0], PB = xb[64];
    float cc0 = 0.f;

    REGION(0, 0, PA, 0);
    REGION(1, 1, PB, 1);
    for (int t = 2; t < SS; t += 2) {
        REGION(t,     0, PA, 1);
        REGION(t + 1, 1, PB, 1);
    }
    if (DM == 1 && w == 0) {   // inline-dense epilogue for h_{SS-1}
        const short8 ha0 = *(const short8*)&hbuf[1][m * HROW + (q << 3)];
        const short8 ha1 = *(const short8*)&hbuf[1][m * HROW + 32 + (q << 3)];
        const f32x4 zz = {0.f, 0.f, 0.f, 0.f};
        const f32x4 z4 = MF(ha1, BD1, MF(ha0, BD0, zz));
        if (m == 0) {
            out[((size_t)((bb << 2) + q) << 10) + SS - 1] =
                sigmoidf_(z4[0] + db0);
        }
    }
}

// ============ Kernel 3: out = sigmoid(h @ dw + db), one thread per (b,t) ===
__global__ __launch_bounds__(256)
void dense_out(const unsigned short* __restrict__ hg,
               const float* __restrict__ dw, const float* __restrict__ db,
               float* __restrict__ out) {
    const int row = blockIdx.x * 256 + threadIdx.x;    // b*1024 + t
    const short8* __restrict__ hr = (const short8*)(hg + (size_t)row * 64);
    float acc = db[0];
#pragma unroll
    for (int jj = 0; jj < 8; ++jj) {
        const short8 v = hr[jj];
#pragma unroll
        for (int k = 0; k < 8; ++k)
            acc += bf2f((unsigned short)v[k]) * dw[jj * 8 + k];
    }
    out[row] = sigmoidf_(acc);
}

// ============ Host ============
extern "C" void kernel_launch(void* const* d_in, const int* in_sizes, int n_in,
                              void* d_out, int out_size, void* d_ws, size_t ws_size,
                              hipStream_t stream) {
    const float* x    = (const float*)d_in[0];
    const float* wk   = (const float*)d_in[1];
    const float* rk   = (const float*)d_in[2];
    const float* bias = (const float*)d_in[3];
    const float* dw   = (const float*)d_in[4];
    const float* db   = (const float*)d_in[5];
    float* out = (float*)d_out;

    const size_t XZ_BYTES = (size_t)262144 * 256 * 2;  // 128 MB
    const size_t HG_BYTES = (size_t)262144 * 64 * 2;   //  32 MB

    uint2* xz = (uint2*)d_ws;
    hipLaunchKernelGGL(xzgemm, dim3(256), dim3(256), 0, stream,
                       x, wk, bias, xz);

    if (ws_size >= XZ_BYTES + HG_BYTES) {
        unsigned short* hg = (unsigned short*)((char*)d_ws + XZ_BYTES);
        hipLaunchKernelGGL((lstm_xz<0>), dim3(NBLK), dim3(256), 0, stream,
                           xz, rk, hg, dw, db, out);
        hipLaunchKernelGGL(dense_out, dim3(1024), dim3(256), 0, stream,
                           hg, dw, db, out);
    } else {
        hipLaunchKernelGGL((lstm_xz<1>), dim3(NBLK), dim3(256), 0, stream,
                           xz, rk, (unsigned short*)nullptr, dw, db, out);
    }
}